// Round 11
// baseline (1449.747 us; speedup 1.0000x reference)
//
#include <hip/hip_runtime.h>

// MDDNet GNN layer — round 11: GEMM2-internal ABLATION.
// R9/R10 established: stage+GEMM1 = 16µs, scatter overhaul ~null ->
// GEMM2 compute ~350µs is the mystery. Probes (garbage-writing, pre-memset):
//   V3 = no scatter (asm-sink acc), V4 = const-B (no per-ks B loads),
//   V5 = const-af (no per-ks LDS reads). V0 = real (R10 structure).
// N=20000, E=320000, D=128, H1=256, H2=512, H3=1024, K3=640.

constexpr int D  = 128;
constexpr int H1 = 256;
constexpr int H2 = 512;
constexpr int H3 = 1024;
constexpr int K3 = D + H2;   // 640

typedef short  bf16x8 __attribute__((ext_vector_type(8)));
typedef ushort u16x8  __attribute__((ext_vector_type(8)));
typedef float  f32x4  __attribute__((ext_vector_type(4)));

__device__ __forceinline__ float leaky(float x) { return x >= 0.f ? x : 0.01f * x; }

__device__ __forceinline__ ushort f2bf(float f) {
    unsigned u = __float_as_uint(f);
    u += 0x7FFFu + ((u >> 16) & 1u);
    return (ushort)(u >> 16);
}

__device__ __forceinline__ int swz(int row, int bytecol) {
    return bytecol ^ ((row & 7) << 4);
}

__device__ __forceinline__ f32x4 mfma16(bf16x8 a, bf16x8 b, f32x4 c) {
    return __builtin_amdgcn_mfma_f32_16x16x32_bf16(a, b, c, 0, 0, 0);
}

__device__ __forceinline__ void gload_lds16(const void* g, void* l) {
    __builtin_amdgcn_global_load_lds(
        (const __attribute__((address_space(1))) void*)g,
        (__attribute__((address_space(3))) void*)l, 16, 0, 0);
}

// ---------------------------------------------------------------------------
// Counting sort by dst.
// ---------------------------------------------------------------------------
__global__ __launch_bounds__(256) void hist_kernel(
    const int* __restrict__ dst, int* __restrict__ cursor, int E)
{
    const int i = blockIdx.x * 256 + threadIdx.x;
    if (i < E) atomicAdd(&cursor[dst[i]], 1);
}

__global__ __launch_bounds__(1024) void scan_kernel(int* __restrict__ cursor, int n)
{
    __shared__ int sums[1024];
    const int tid  = threadIdx.x;
    const int base = tid * 20;
    int v[20];
    int s = 0;
    #pragma unroll
    for (int i = 0; i < 20; ++i) {
        const int idx = base + i;
        v[i] = (idx < n) ? cursor[idx] : 0;
        s += v[i];
    }
    sums[tid] = s;
    __syncthreads();
    int acc = s;
    for (int d = 1; d < 1024; d <<= 1) {
        const int t = (tid >= d) ? sums[tid - d] : 0;
        __syncthreads();
        acc += t;
        sums[tid] = acc;
        __syncthreads();
    }
    int run = acc - s;
    #pragma unroll
    for (int i = 0; i < 20; ++i) {
        const int idx = base + i;
        if (idx < n) cursor[idx] = run;
        run += v[i];
    }
}

__global__ __launch_bounds__(256) void scatter_kernel(
    const int* __restrict__ src, const int* __restrict__ dst,
    int* __restrict__ cursor, int* __restrict__ se, int* __restrict__ de,
    int* __restrict__ pe, int E)
{
    const int i = blockIdx.x * 256 + threadIdx.x;
    if (i < E) {
        const int d   = dst[i];
        const int pos = atomicAdd(&cursor[d], 1);
        se[pos] = src[i];
        de[pos] = d;
        pe[pos] = i;
    }
}

// ---------------------------------------------------------------------------
// gather_t: t[pos] = bf16(x0[se[pos]] * ea[pe[pos]]), pre-swizzled chunks.
// ---------------------------------------------------------------------------
__global__ __launch_bounds__(256) void gather_t(
    const float* __restrict__ x0, const float* __restrict__ ea,
    const int* __restrict__ se, const int* __restrict__ pe,
    ushort* __restrict__ t)
{
    const int gid  = blockIdx.x * 256 + threadIdx.x;
    const int e    = gid >> 4;
    const int slot = gid & 15;
    const int s = se[e];
    const int p = pe[e];
    const float4* xp = (const float4*)(x0 + (size_t)s * D + slot * 8);
    const float4* gp = (const float4*)(ea + (size_t)p * D + slot * 8);
    const float4 xa = xp[0], xb = xp[1];
    const float4 ga = gp[0], gb = gp[1];
    u16x8 u;
    u[0] = f2bf(xa.x * ga.x); u[1] = f2bf(xa.y * ga.y);
    u[2] = f2bf(xa.z * ga.z); u[3] = f2bf(xa.w * ga.w);
    u[4] = f2bf(xb.x * gb.x); u[5] = f2bf(xb.y * gb.y);
    u[6] = f2bf(xb.z * gb.z); u[7] = f2bf(xb.w * gb.w);
    const int slot_w = slot ^ (e & 7);
    *(u16x8*)(t + (size_t)e * D + slot_w * 8) = u;
}

// ---------------------------------------------------------------------------
// Pack fp32 W[K][Nc] into bf16 B-fragment tile order.
// ---------------------------------------------------------------------------
__global__ __launch_bounds__(256) void pack_weights(
    const float* __restrict__ W, ushort* __restrict__ Wp, int K, int Nc)
{
    const int KT    = K >> 5;
    const int total = (Nc >> 4) * KT * 64;
    const int idx   = blockIdx.x * 256 + threadIdx.x;
    if (idx >= total) return;
    const int l   = idx & 63;
    const int tt  = idx >> 6;
    const int ks  = tt % KT;
    const int ni  = tt / KT;
    const int col = ni * 16 + (l & 15);
    const int k0  = ks * 32 + (l >> 4) * 8;
    u16x8 u;
    #pragma unroll
    for (int j = 0; j < 8; ++j) u[j] = f2bf(W[(size_t)(k0 + j) * Nc + col]);
    *(u16x8*)(Wp + (size_t)idx * 8) = u;
}

// ---------------------------------------------------------------------------
// Edge GEMM (R10 LDS-seg structure), templated for GEMM2-internal ablation.
// V=0 real; V=3 no scatter (asm sink); V=4 const-B; V=5 const-af.
// ---------------------------------------------------------------------------
constexpr int TE = 64;
constexpr int SEGW = 260;

template<int V>
__global__ __launch_bounds__(512) void edge_gemm_mfma(
    const ushort* __restrict__ t, const int* __restrict__ de,
    const ushort* __restrict__ W1p, const float* __restrict__ b1,
    const ushort* __restrict__ W2p, const float* __restrict__ b2,
    float* __restrict__ aggr)
{
    __shared__ __align__(16) ushort t_lds[TE * D];     // 16 KB
    __shared__ __align__(16) ushort m1_lds[TE * H1];   // 32 KB
    __shared__ float seg[TE * SEGW];                   // 66.5 KB
    __shared__ int didx[TE];
    __shared__ int rank_l[TE];
    __shared__ int seg2dst[TE];
    __shared__ int nd_s;

    const int tid  = threadIdx.x;
    const int e0   = blockIdx.x * TE;
    const int lane = tid & 63;
    const int w    = tid >> 6;
    const int lr   = lane & 15;
    const int lg   = lane >> 4;

    const ushort* gsrc = t + (size_t)e0 * D;
    #pragma unroll
    for (int i = 0; i < 2; ++i) {
        const int c = (w * 2 + i) * 64 + lane;
        gload_lds16(gsrc + (size_t)c * 8, t_lds + (w * 2 + i) * 512);
    }
    if (tid < TE) didx[tid] = de[e0 + tid];
    __syncthreads();

    if (tid < 64) {
        const int flag = (tid > 0 && didx[tid] != didx[tid - 1]) ? 1 : 0;
        int v = flag;
        #pragma unroll
        for (int d = 1; d < 64; d <<= 1) {
            const int x = __shfl_up(v, d);
            if (lane >= d) v += x;
        }
        rank_l[tid] = v;
        seg2dst[v]  = didx[tid];
        if (tid == 63) nd_s = v + 1;
    }

    // ---- GEMM1 (identical across variants)
    {
        f32x4 acc[4][2];
        #pragma unroll
        for (int ntl = 0; ntl < 2; ++ntl) {
            const float b = b1[(w * 2 + ntl) * 16 + lr];
            #pragma unroll
            for (int mt = 0; mt < 4; ++mt) acc[mt][ntl] = (f32x4){b, b, b, b};
        }
        #pragma unroll
        for (int ks = 0; ks < 4; ++ks) {
            bf16x8 af[4];
            #pragma unroll
            for (int mt = 0; mt < 4; ++mt) {
                const int row = mt * 16 + lr;
                af[mt] = *(const bf16x8*)((const char*)t_lds + row * 256 +
                                          swz(row, ks * 64 + lg * 16));
            }
            #pragma unroll
            for (int ntl = 0; ntl < 2; ++ntl) {
                const bf16x8 bf = *(const bf16x8*)(W1p +
                    ((size_t)((w * 2 + ntl) * 4 + ks) * 64 + lane) * 8);
                #pragma unroll
                for (int mt = 0; mt < 4; ++mt)
                    acc[mt][ntl] = mfma16(af[mt], bf, acc[mt][ntl]);
            }
        }
        #pragma unroll
        for (int mt = 0; mt < 4; ++mt)
            #pragma unroll
            for (int ntl = 0; ntl < 2; ++ntl)
                #pragma unroll
                for (int r = 0; r < 4; ++r) {
                    const int row = mt * 16 + lg * 4 + r;
                    const int col = (w * 2 + ntl) * 16 + lr;
                    *(ushort*)((char*)m1_lds + row * 512 + swz(row, col * 2)) =
                        f2bf(leaky(acc[mt][ntl][r]));
                }
    }
    __syncthreads();

    const int nd = nd_s;
    int rk[4][4];
    #pragma unroll
    for (int mt = 0; mt < 4; ++mt)
        #pragma unroll
        for (int r = 0; r < 4; ++r)
            rk[mt][r] = rank_l[mt * 16 + lg * 4 + r];

    // loop-invariant fragments for V4/V5
    bf16x8 bconst = *(const bf16x8*)(W2p + (size_t)lane * 8);
    bf16x8 afconst[4];
    #pragma unroll
    for (int mt = 0; mt < 4; ++mt)
        afconst[mt] = *(const bf16x8*)((const char*)m1_lds +
                                       (mt * 16 + lr) * 512 +
                                       swz(mt * 16 + lr, lg * 16));

    float sink = 0.f;

    #pragma unroll
    for (int p = 0; p < 2; ++p) {
        if constexpr (V != 3) {
            for (int i = tid; i < nd * SEGW; i += 512) seg[i] = 0.f;
            __syncthreads();
        }

        f32x4 acc[4][2];
        #pragma unroll
        for (int ntl = 0; ntl < 2; ++ntl) {
            const int nt = p * 16 + w * 2 + ntl;
            const float b = b2[nt * 16 + lr];
            #pragma unroll
            for (int mt = 0; mt < 4; ++mt) acc[mt][ntl] = (f32x4){b, b, b, b};
        }
        #pragma unroll
        for (int ks = 0; ks < 8; ++ks) {
            bf16x8 af[4];
            if constexpr (V == 5) {
                #pragma unroll
                for (int mt = 0; mt < 4; ++mt) af[mt] = afconst[mt];
            } else {
                #pragma unroll
                for (int mt = 0; mt < 4; ++mt) {
                    const int row = mt * 16 + lr;
                    af[mt] = *(const bf16x8*)((const char*)m1_lds + row * 512 +
                                              swz(row, ks * 64 + lg * 16));
                }
            }
            #pragma unroll
            for (int ntl = 0; ntl < 2; ++ntl) {
                bf16x8 bf;
                if constexpr (V == 4) {
                    bf = bconst;
                } else {
                    const int nt = p * 16 + w * 2 + ntl;
                    bf = *(const bf16x8*)(W2p +
                        ((size_t)(nt * 8 + ks) * 64 + lane) * 8);
                }
                #pragma unroll
                for (int mt = 0; mt < 4; ++mt)
                    acc[mt][ntl] = mfma16(af[mt], bf, acc[mt][ntl]);
            }
        }

        if constexpr (V == 3) {
            #pragma unroll
            for (int mt = 0; mt < 4; ++mt)
                #pragma unroll
                for (int ntl = 0; ntl < 2; ++ntl)
                    #pragma unroll
                    for (int r = 0; r < 4; ++r)
                        sink += acc[mt][ntl][r];
        } else {
            #pragma unroll
            for (int mt = 0; mt < 4; ++mt)
                #pragma unroll
                for (int ntl = 0; ntl < 2; ++ntl) {
                    const int col = (w * 2 + ntl) * 16 + lr;
                    float s = leaky(acc[mt][ntl][0]);
                    #pragma unroll
                    for (int r = 1; r < 4; ++r) {
                        const float v = leaky(acc[mt][ntl][r]);
                        if (rk[mt][r] == rk[mt][r - 1]) {
                            s += v;
                        } else {
                            atomicAdd(&seg[rk[mt][r - 1] * SEGW + col], s);
                            s = v;
                        }
                    }
                    atomicAdd(&seg[rk[mt][3] * SEGW + col], s);
                }
            __syncthreads();
            {
                const int col = tid & 255;
                for (int s = tid >> 8; s < nd; s += 2)
                    atomicAdd(&aggr[(size_t)seg2dst[s] * H2 + p * 256 + col],
                              seg[s * SEGW + col]);
            }
            __syncthreads();
        }
    }

    if constexpr (V == 3) {
        asm volatile("" :: "v"(sink));
    }
}

// ---------------------------------------------------------------------------
// h[N][1024] = bf16(leaky(concat(x0, aggr) @ W3 + b3)); 8 waves / 512 thr.
// ---------------------------------------------------------------------------
constexpr int TN = 32;

__global__ __launch_bounds__(512) void node_mlp1_mfma(
    const float* __restrict__ x0, const float* __restrict__ aggr,
    const ushort* __restrict__ W3p, const float* __restrict__ b3,
    ushort* __restrict__ h)
{
    __shared__ __align__(16) ushort a_lds[TN * K3];  // 40 KB
    const int tid  = threadIdx.x;
    const int n0   = blockIdx.x * TN;
    const int ch   = blockIdx.y;
    const int lane = tid & 63;
    const int w    = tid >> 6;
    const int lr   = lane & 15;
    const int lg   = lane >> 4;

    #pragma unroll
    for (int i = 0; i < 5; ++i) {
        const int c    = i * 512 + tid;
        const int row  = c / 80;
        const int slot = c % 80;
        const float* sp = (slot < 16)
            ? x0   + (size_t)(n0 + row) * D  + slot * 8
            : aggr + (size_t)(n0 + row) * H2 + (slot - 16) * 8;
        const float4 va = ((const float4*)sp)[0];
        const float4 vb = ((const float4*)sp)[1];
        u16x8 u;
        u[0] = f2bf(va.x); u[1] = f2bf(va.y); u[2] = f2bf(va.z); u[3] = f2bf(va.w);
        u[4] = f2bf(vb.x); u[5] = f2bf(vb.y); u[6] = f2bf(vb.z); u[7] = f2bf(vb.w);
        *(u16x8*)((char*)a_lds + row * 1280 + swz(row, slot * 16)) = u;
    }
    __syncthreads();

    f32x4 acc[2][4];
    #pragma unroll
    for (int ntl = 0; ntl < 4; ++ntl) {
        const int colg = ch * 512 + (w * 4 + ntl) * 16 + lr;
        const float b = b3[colg];
        #pragma unroll
        for (int mt = 0; mt < 2; ++mt) acc[mt][ntl] = (f32x4){b, b, b, b};
    }
    for (int ks = 0; ks < 20; ++ks) {
        bf16x8 af[2];
        #pragma unroll
        for (int mt = 0; mt < 2; ++mt) {
            const int row = mt * 16 + lr;
            af[mt] = *(const bf16x8*)((const char*)a_lds + row * 1280 +
                                      swz(row, ks * 64 + lg * 16));
        }
        #pragma unroll
        for (int ntl = 0; ntl < 4; ++ntl) {
            const int nt = ch * 32 + w * 4 + ntl;
            const bf16x8 bf = *(const bf16x8*)(W3p +
                ((size_t)(nt * 20 + ks) * 64 + lane) * 8);
            #pragma unroll
            for (int mt = 0; mt < 2; ++mt)
                acc[mt][ntl] = mfma16(af[mt], bf, acc[mt][ntl]);
        }
    }
    #pragma unroll
    for (int mt = 0; mt < 2; ++mt)
        #pragma unroll
        for (int ntl = 0; ntl < 4; ++ntl) {
            const int colg = ch * 512 + (w * 4 + ntl) * 16 + lr;
            #pragma unroll
            for (int r = 0; r < 4; ++r) {
                const int row = n0 + mt * 16 + lg * 4 + r;
                h[(size_t)row * H3 + colg] = f2bf(leaky(acc[mt][ntl][r]));
            }
        }
}

// ---------------------------------------------------------------------------
// out = ((h @ W4 + b4)·BN + x0) / 2
// ---------------------------------------------------------------------------
__global__ __launch_bounds__(256) void node_mlp2_mfma(
    const ushort* __restrict__ h, const float* __restrict__ x0,
    const ushort* __restrict__ W4p, const float* __restrict__ b4,
    const float* __restrict__ gamma, const float* __restrict__ beta,
    const float* __restrict__ mean, const float* __restrict__ var,
    float* __restrict__ out)
{
    const int tid  = threadIdx.x;
    const int n0   = blockIdx.x * TN;
    const int lane = tid & 63;
    const int w    = tid >> 6;
    const int lr   = lane & 15;
    const int lg   = lane >> 4;

    f32x4 acc[2][2];
    #pragma unroll
    for (int ntl = 0; ntl < 2; ++ntl) {
        const float b = b4[(w * 2 + ntl) * 16 + lr];
        #pragma unroll
        for (int mt = 0; mt < 2; ++mt) acc[mt][ntl] = (f32x4){b, b, b, b};
    }
    for (int ks = 0; ks < 32; ++ks) {
        bf16x8 af[2];
        #pragma unroll
        for (int mt = 0; mt < 2; ++mt)
            af[mt] = *(const bf16x8*)(h + (size_t)(n0 + mt * 16 + lr) * H3 +
                                      ks * 32 + lg * 8);
        #pragma unroll
        for (int ntl = 0; ntl < 2; ++ntl) {
            const bf16x8 bf = *(const bf16x8*)(W4p +
                ((size_t)((w * 2 + ntl) * 32 + ks) * 64 + lane) * 8);
            #pragma unroll
            for (int mt = 0; mt < 2; ++mt)
                acc[mt][ntl] = mfma16(af[mt], bf, acc[mt][ntl]);
        }
    }
    #pragma unroll
    for (int ntl = 0; ntl < 2; ++ntl) {
        const int col = (w * 2 + ntl) * 16 + lr;
        const float sc = gamma[col] * rsqrtf(var[col] + 1e-5f);
        const float bo = beta[col] - mean[col] * sc;
        #pragma unroll
        for (int mt = 0; mt < 2; ++mt)
            #pragma unroll
            for (int r = 0; r < 4; ++r) {
                const int row = n0 + mt * 16 + lg * 4 + r;
                const float v = acc[mt][ntl][r] * sc + bo;
                out[(size_t)row * D + col] =
                    0.5f * (v + x0[(size_t)row * D + col]);
            }
    }
}

extern "C" void kernel_launch(void* const* d_in, const int* in_sizes, int n_in,
                              void* d_out, int out_size, void* d_ws, size_t ws_size,
                              hipStream_t stream)
{
    const float* x0    = (const float*)d_in[0];
    const int*   ei    = (const int*)d_in[1];
    const float* ea    = (const float*)d_in[2];
    const float* W1    = (const float*)d_in[3];
    const float* b1    = (const float*)d_in[4];
    const float* W2    = (const float*)d_in[5];
    const float* b2    = (const float*)d_in[6];
    const float* W3    = (const float*)d_in[7];
    const float* b3    = (const float*)d_in[8];
    const float* W4    = (const float*)d_in[9];
    const float* b4    = (const float*)d_in[10];
    const float* gamma = (const float*)d_in[11];
    const float* beta  = (const float*)d_in[12];
    const float* mean  = (const float*)d_in[13];
    const float* var   = (const float*)d_in[14];
    float* out = (float*)d_out;

    const int N = in_sizes[0] / D;   // 20000
    const int E = in_sizes[2] / D;   // 320000
    const int* src = ei;
    const int* dst = ei + E;

    char* ws = (char*)d_ws;
    float*  aggr = (float*)ws;
    ushort* t    = (ushort*)(ws + (size_t)N * H2 * 4);
    ushort* h    = t;   // alias: node_mlp1 writes h AFTER edge_gemm consumed t
    char*   p2   = (char*)(t + (size_t)E * D);
    int* cursor = (int*)p2;
    int* se     = cursor + N;
    int* de     = se + E;
    int* pe     = de + E;
    ushort* W1p = (ushort*)(pe + E);
    ushort* W2p = W1p + (size_t)(D  / 32) * (H1 / 16) * 512;
    ushort* W3p = W2p + (size_t)(H1 / 32) * (H2 / 16) * 512;
    ushort* W4p = W3p + (size_t)(K3 / 32) * (H3 / 16) * 512;

    hipMemsetAsync(cursor, 0, (size_t)N * sizeof(int), stream);

    pack_weights<<<(4096  + 255) / 256, 256, 0, stream>>>(W1, W1p, D,  H1);
    pack_weights<<<(16384 + 255) / 256, 256, 0, stream>>>(W2, W2p, H1, H2);
    pack_weights<<<(81920 + 255) / 256, 256, 0, stream>>>(W3, W3p, K3, H3);
    pack_weights<<<(16384 + 255) / 256, 256, 0, stream>>>(W4, W4p, H3, D);

    hist_kernel<<<(E + 255) / 256, 256, 0, stream>>>(dst, cursor, E);
    scan_kernel<<<1, 1024, 0, stream>>>(cursor, N);
    scatter_kernel<<<(E + 255) / 256, 256, 0, stream>>>(src, dst, cursor,
                                                        se, de, pe, E);

    gather_t<<<E / 16, 256, 0, stream>>>(x0, ea, se, pe, t);

    // ---- ablation probes (garbage into aggr; memset follows) ----
    edge_gemm_mfma<3><<<E / TE, 512, 0, stream>>>(t, de, W1p, b1, W2p, b2, aggr);
    edge_gemm_mfma<4><<<E / TE, 512, 0, stream>>>(t, de, W1p, b1, W2p, b2, aggr);
    edge_gemm_mfma<5><<<E / TE, 512, 0, stream>>>(t, de, W1p, b1, W2p, b2, aggr);

    // ---- real pipeline ----
    hipMemsetAsync(aggr, 0, (size_t)N * H2 * sizeof(float), stream);
    edge_gemm_mfma<0><<<E / TE, 512, 0, stream>>>(t, de, W1p, b1, W2p, b2, aggr);

    dim3 g1(N / TN, 2);
    node_mlp1_mfma<<<g1, 512, 0, stream>>>(x0, aggr, W3p, b3, h);
    node_mlp2_mfma<<<N / TN, 256, 0, stream>>>(h, x0, W4p, b4, gamma, beta, mean, var, out);
}

// Round 12
// 572.584 us; speedup vs baseline: 2.5319x; 2.5319x over previous
//
#include <hip/hip_runtime.h>

// MDDNet GNN layer — round 12: operand-swapped GEMM2 (m2^T = W2^T @ m1^T)
// + lane-segmented shuffle reduction. R11 ablation: B-loads null (V4≈V0),
// MFMA ≤ ~215, af-reads + scatter jointly ~360 of 397µs -> kill both:
// edge-major C fragments (edge = lane&15), monotone ranks -> 4-step shfl
// segment-sum, head-lane collision-free atomics. No seg LDS, no ds_add,
// 2 barriers total. N=20000, E=320000, D=128, H1=256, H2=512, H3=1024.

constexpr int D  = 128;
constexpr int H1 = 256;
constexpr int H2 = 512;
constexpr int H3 = 1024;
constexpr int K3 = D + H2;   // 640

typedef short  bf16x8 __attribute__((ext_vector_type(8)));
typedef ushort u16x8  __attribute__((ext_vector_type(8)));
typedef float  f32x4  __attribute__((ext_vector_type(4)));

__device__ __forceinline__ float leaky(float x) { return x >= 0.f ? x : 0.01f * x; }

__device__ __forceinline__ ushort f2bf(float f) {
    unsigned u = __float_as_uint(f);
    u += 0x7FFFu + ((u >> 16) & 1u);
    return (ushort)(u >> 16);
}

__device__ __forceinline__ int swz(int row, int bytecol) {
    return bytecol ^ ((row & 7) << 4);
}

__device__ __forceinline__ f32x4 mfma16(bf16x8 a, bf16x8 b, f32x4 c) {
    return __builtin_amdgcn_mfma_f32_16x16x32_bf16(a, b, c, 0, 0, 0);
}

__device__ __forceinline__ void gload_lds16(const void* g, void* l) {
    __builtin_amdgcn_global_load_lds(
        (const __attribute__((address_space(1))) void*)g,
        (__attribute__((address_space(3))) void*)l, 16, 0, 0);
}

// ---------------------------------------------------------------------------
// Counting sort by dst.
// ---------------------------------------------------------------------------
__global__ __launch_bounds__(256) void hist_kernel(
    const int* __restrict__ dst, int* __restrict__ cursor, int E)
{
    const int i = blockIdx.x * 256 + threadIdx.x;
    if (i < E) atomicAdd(&cursor[dst[i]], 1);
}

__global__ __launch_bounds__(1024) void scan_kernel(int* __restrict__ cursor, int n)
{
    __shared__ int sums[1024];
    const int tid  = threadIdx.x;
    const int base = tid * 20;
    int v[20];
    int s = 0;
    #pragma unroll
    for (int i = 0; i < 20; ++i) {
        const int idx = base + i;
        v[i] = (idx < n) ? cursor[idx] : 0;
        s += v[i];
    }
    sums[tid] = s;
    __syncthreads();
    int acc = s;
    for (int d = 1; d < 1024; d <<= 1) {
        const int t = (tid >= d) ? sums[tid - d] : 0;
        __syncthreads();
        acc += t;
        sums[tid] = acc;
        __syncthreads();
    }
    int run = acc - s;
    #pragma unroll
    for (int i = 0; i < 20; ++i) {
        const int idx = base + i;
        if (idx < n) cursor[idx] = run;
        run += v[i];
    }
}

__global__ __launch_bounds__(256) void scatter_kernel(
    const int* __restrict__ src, const int* __restrict__ dst,
    int* __restrict__ cursor, int* __restrict__ se, int* __restrict__ de,
    int* __restrict__ pe, int E)
{
    const int i = blockIdx.x * 256 + threadIdx.x;
    if (i < E) {
        const int d   = dst[i];
        const int pos = atomicAdd(&cursor[d], 1);
        se[pos] = src[i];
        de[pos] = d;
        pe[pos] = i;
    }
}

// ---------------------------------------------------------------------------
// gather_t: t[pos] = bf16(x0[se[pos]] * ea[pe[pos]]), pre-swizzled chunks.
// ---------------------------------------------------------------------------
__global__ __launch_bounds__(256) void gather_t(
    const float* __restrict__ x0, const float* __restrict__ ea,
    const int* __restrict__ se, const int* __restrict__ pe,
    ushort* __restrict__ t)
{
    const int gid  = blockIdx.x * 256 + threadIdx.x;
    const int e    = gid >> 4;
    const int slot = gid & 15;
    const int s = se[e];
    const int p = pe[e];
    const float4* xp = (const float4*)(x0 + (size_t)s * D + slot * 8);
    const float4* gp = (const float4*)(ea + (size_t)p * D + slot * 8);
    const float4 xa = xp[0], xb = xp[1];
    const float4 ga = gp[0], gb = gp[1];
    u16x8 u;
    u[0] = f2bf(xa.x * ga.x); u[1] = f2bf(xa.y * ga.y);
    u[2] = f2bf(xa.z * ga.z); u[3] = f2bf(xa.w * ga.w);
    u[4] = f2bf(xb.x * gb.x); u[5] = f2bf(xb.y * gb.y);
    u[6] = f2bf(xb.z * gb.z); u[7] = f2bf(xb.w * gb.w);
    const int slot_w = slot ^ (e & 7);
    *(u16x8*)(t + (size_t)e * D + slot_w * 8) = u;
}

// ---------------------------------------------------------------------------
// Pack fp32 W[K][Nc] into bf16 fragment tile order. (The B-fragment layout
// is simultaneously the A-fragment layout of W^T — reused by swapped GEMM2.)
// ---------------------------------------------------------------------------
__global__ __launch_bounds__(256) void pack_weights(
    const float* __restrict__ W, ushort* __restrict__ Wp, int K, int Nc)
{
    const int KT    = K >> 5;
    const int total = (Nc >> 4) * KT * 64;
    const int idx   = blockIdx.x * 256 + threadIdx.x;
    if (idx >= total) return;
    const int l   = idx & 63;
    const int tt  = idx >> 6;
    const int ks  = tt % KT;
    const int ni  = tt / KT;
    const int col = ni * 16 + (l & 15);
    const int k0  = ks * 32 + (l >> 4) * 8;
    u16x8 u;
    #pragma unroll
    for (int j = 0; j < 8; ++j) u[j] = f2bf(W[(size_t)(k0 + j) * Nc + col]);
    *(u16x8*)(Wp + (size_t)idx * 8) = u;
}

// ---------------------------------------------------------------------------
// Edge GEMM: stage -> GEMM1 (m1 to LDS, proven 16µs) -> swapped GEMM2
// (D[h2][e], e = lane&15) -> shfl segment-sum -> head-lane atomics.
// TE=64, 512 threads, 8 waves, LDS ~49.7KB.
// ---------------------------------------------------------------------------
constexpr int TE = 64;

__global__ __launch_bounds__(512) void edge_gemm_mfma(
    const ushort* __restrict__ t, const int* __restrict__ de,
    const ushort* __restrict__ W1p, const float* __restrict__ b1,
    const ushort* __restrict__ W2p, const float* __restrict__ b2,
    float* __restrict__ aggr)
{
    __shared__ __align__(16) ushort t_lds[TE * D];     // 16 KB
    __shared__ __align__(16) ushort m1_lds[TE * H1];   // 32 KB
    __shared__ int didx[TE];
    __shared__ int rank_l[TE];

    const int tid  = threadIdx.x;
    const int e0   = blockIdx.x * TE;
    const int lane = tid & 63;
    const int w    = tid >> 6;     // 0..7
    const int lr   = lane & 15;
    const int lg   = lane >> 4;

    // async stage: 1024 x 16B chunks, 2 per thread
    const ushort* gsrc = t + (size_t)e0 * D;
    #pragma unroll
    for (int i = 0; i < 2; ++i) {
        const int c = (w * 2 + i) * 64 + lane;
        gload_lds16(gsrc + (size_t)c * 8, t_lds + (w * 2 + i) * 512);
    }
    if (tid < TE) didx[tid] = de[e0 + tid];
    __syncthreads();

    // wave 0: rank prefix over dst changes (monotone since dst-sorted)
    if (tid < 64) {
        const int flag = (tid > 0 && didx[tid] != didx[tid - 1]) ? 1 : 0;
        int v = flag;
        #pragma unroll
        for (int d = 1; d < 64; d <<= 1) {
            const int x = __shfl_up(v, d);
            if (lane >= d) v += x;
        }
        rank_l[tid] = v;
    }

    // ---- GEMM1: m1[64][256] = leaky(t @ W1 + b1); wave owns ntiles {2w,2w+1}
    {
        f32x4 acc[4][2];
        #pragma unroll
        for (int ntl = 0; ntl < 2; ++ntl) {
            const float b = b1[(w * 2 + ntl) * 16 + lr];
            #pragma unroll
            for (int mt = 0; mt < 4; ++mt) acc[mt][ntl] = (f32x4){b, b, b, b};
        }
        #pragma unroll
        for (int ks = 0; ks < 4; ++ks) {
            bf16x8 af[4];
            #pragma unroll
            for (int mt = 0; mt < 4; ++mt) {
                const int row = mt * 16 + lr;
                af[mt] = *(const bf16x8*)((const char*)t_lds + row * 256 +
                                          swz(row, ks * 64 + lg * 16));
            }
            #pragma unroll
            for (int ntl = 0; ntl < 2; ++ntl) {
                const bf16x8 bf = *(const bf16x8*)(W1p +
                    ((size_t)((w * 2 + ntl) * 4 + ks) * 64 + lane) * 8);
                #pragma unroll
                for (int mt = 0; mt < 4; ++mt)
                    acc[mt][ntl] = mfma16(af[mt], bf, acc[mt][ntl]);
            }
        }
        #pragma unroll
        for (int mt = 0; mt < 4; ++mt)
            #pragma unroll
            for (int ntl = 0; ntl < 2; ++ntl)
                #pragma unroll
                for (int r = 0; r < 4; ++r) {
                    const int row = mt * 16 + lg * 4 + r;
                    const int col = (w * 2 + ntl) * 16 + lr;
                    *(ushort*)((char*)m1_lds + row * 512 + swz(row, col * 2)) =
                        f2bf(leaky(acc[mt][ntl][r]));
                }
    }
    __syncthreads();   // m1 + rank_l ready

    // ---- swapped GEMM2: D[i][e] = (W2^T @ m1^T)[i][e] + b2[i]
    // A = W2p chunks (pack layout doubles as A-frag of W2^T)
    // B = m1 rows as edge-columns: col = lane&15 = e
    // wave w owns H2 rows i in [(w*4+mt)*16, +16), mt = 0..3; et = 0..3 edges.
    f32x4 acc2[4][4];   // [mt][et]
    #pragma unroll
    for (int mt = 0; mt < 4; ++mt) {
        const float4 bb = *(const float4*)(b2 + (w * 4 + mt) * 16 + lg * 4);
        #pragma unroll
        for (int et = 0; et < 4; ++et)
            acc2[mt][et] = (f32x4){bb.x, bb.y, bb.z, bb.w};
    }
    #pragma unroll
    for (int ks = 0; ks < 8; ++ks) {
        bf16x8 mf[4];
        #pragma unroll
        for (int et = 0; et < 4; ++et) {
            const int e = et * 16 + lr;
            mf[et] = *(const bf16x8*)((const char*)m1_lds + e * 512 +
                                      swz(e, ks * 64 + lg * 16));
        }
        #pragma unroll
        for (int mt = 0; mt < 4; ++mt) {
            const bf16x8 wf = *(const bf16x8*)(W2p +
                ((size_t)((w * 4 + mt) * 8 + ks) * 64 + lane) * 8);
            #pragma unroll
            for (int et = 0; et < 4; ++et)
                acc2[mt][et] = mfma16(wf, mf[et], acc2[mt][et]);
        }
    }

    // ---- epilogue: leaky -> width-16 segmented suffix-sum (ranks monotone)
    //      -> head lanes do collision-free global atomics.
    #pragma unroll
    for (int et = 0; et < 4; ++et) {
        const int e  = et * 16 + lr;
        const int rk = rank_l[e];
        const int dn = didx[e];
        const int rkp = __shfl_up(rk, 1, 16);
        const bool head = (lr == 0) || (rk != rkp);
        bool ok[4];
        #pragma unroll
        for (int s = 0; s < 4; ++s) {
            const int d   = 1 << s;
            const int rk2 = __shfl_down(rk, d, 16);
            ok[s] = (lr + d < 16) && (rk2 == rk);
        }
        #pragma unroll
        for (int mt = 0; mt < 4; ++mt) {
            float v[4];
            #pragma unroll
            for (int r = 0; r < 4; ++r) v[r] = leaky(acc2[mt][et][r]);
            #pragma unroll
            for (int s = 0; s < 4; ++s) {
                const int d = 1 << s;
                #pragma unroll
                for (int r = 0; r < 4; ++r) {
                    const float tt = __shfl_down(v[r], d, 16);
                    if (ok[s]) v[r] += tt;
                }
            }
            if (head) {
                float* base = &aggr[(size_t)dn * H2 + (w * 4 + mt) * 16 + lg * 4];
                #pragma unroll
                for (int r = 0; r < 4; ++r) atomicAdd(base + r, v[r]);
            }
        }
    }
}

// ---------------------------------------------------------------------------
// h[N][1024] = bf16(leaky(concat(x0, aggr) @ W3 + b3)); 8 waves / 512 thr.
// ---------------------------------------------------------------------------
constexpr int TN = 32;

__global__ __launch_bounds__(512) void node_mlp1_mfma(
    const float* __restrict__ x0, const float* __restrict__ aggr,
    const ushort* __restrict__ W3p, const float* __restrict__ b3,
    ushort* __restrict__ h)
{
    __shared__ __align__(16) ushort a_lds[TN * K3];  // 40 KB
    const int tid  = threadIdx.x;
    const int n0   = blockIdx.x * TN;
    const int ch   = blockIdx.y;
    const int lane = tid & 63;
    const int w    = tid >> 6;
    const int lr   = lane & 15;
    const int lg   = lane >> 4;

    #pragma unroll
    for (int i = 0; i < 5; ++i) {
        const int c    = i * 512 + tid;
        const int row  = c / 80;
        const int slot = c % 80;
        const float* sp = (slot < 16)
            ? x0   + (size_t)(n0 + row) * D  + slot * 8
            : aggr + (size_t)(n0 + row) * H2 + (slot - 16) * 8;
        const float4 va = ((const float4*)sp)[0];
        const float4 vb = ((const float4*)sp)[1];
        u16x8 u;
        u[0] = f2bf(va.x); u[1] = f2bf(va.y); u[2] = f2bf(va.z); u[3] = f2bf(va.w);
        u[4] = f2bf(vb.x); u[5] = f2bf(vb.y); u[6] = f2bf(vb.z); u[7] = f2bf(vb.w);
        *(u16x8*)((char*)a_lds + row * 1280 + swz(row, slot * 16)) = u;
    }
    __syncthreads();

    f32x4 acc[2][4];
    #pragma unroll
    for (int ntl = 0; ntl < 4; ++ntl) {
        const int colg = ch * 512 + (w * 4 + ntl) * 16 + lr;
        const float b = b3[colg];
        #pragma unroll
        for (int mt = 0; mt < 2; ++mt) acc[mt][ntl] = (f32x4){b, b, b, b};
    }
    for (int ks = 0; ks < 20; ++ks) {
        bf16x8 af[2];
        #pragma unroll
        for (int mt = 0; mt < 2; ++mt) {
            const int row = mt * 16 + lr;
            af[mt] = *(const bf16x8*)((const char*)a_lds + row * 1280 +
                                      swz(row, ks * 64 + lg * 16));
        }
        #pragma unroll
        for (int ntl = 0; ntl < 4; ++ntl) {
            const int nt = ch * 32 + w * 4 + ntl;
            const bf16x8 bf = *(const bf16x8*)(W3p +
                ((size_t)(nt * 20 + ks) * 64 + lane) * 8);
            #pragma unroll
            for (int mt = 0; mt < 2; ++mt)
                acc[mt][ntl] = mfma16(af[mt], bf, acc[mt][ntl]);
        }
    }
    #pragma unroll
    for (int mt = 0; mt < 2; ++mt)
        #pragma unroll
        for (int ntl = 0; ntl < 4; ++ntl) {
            const int colg = ch * 512 + (w * 4 + ntl) * 16 + lr;
            #pragma unroll
            for (int r = 0; r < 4; ++r) {
                const int row = n0 + mt * 16 + lg * 4 + r;
                h[(size_t)row * H3 + colg] = f2bf(leaky(acc[mt][ntl][r]));
            }
        }
}

// ---------------------------------------------------------------------------
// out = ((h @ W4 + b4)·BN + x0) / 2
// ---------------------------------------------------------------------------
__global__ __launch_bounds__(256) void node_mlp2_mfma(
    const ushort* __restrict__ h, const float* __restrict__ x0,
    const ushort* __restrict__ W4p, const float* __restrict__ b4,
    const float* __restrict__ gamma, const float* __restrict__ beta,
    const float* __restrict__ mean, const float* __restrict__ var,
    float* __restrict__ out)
{
    const int tid  = threadIdx.x;
    const int n0   = blockIdx.x * TN;
    const int lane = tid & 63;
    const int w    = tid >> 6;
    const int lr   = lane & 15;
    const int lg   = lane >> 4;

    f32x4 acc[2][2];
    #pragma unroll
    for (int ntl = 0; ntl < 2; ++ntl) {
        const float b = b4[(w * 2 + ntl) * 16 + lr];
        #pragma unroll
        for (int mt = 0; mt < 2; ++mt) acc[mt][ntl] = (f32x4){b, b, b, b};
    }
    for (int ks = 0; ks < 32; ++ks) {
        bf16x8 af[2];
        #pragma unroll
        for (int mt = 0; mt < 2; ++mt)
            af[mt] = *(const bf16x8*)(h + (size_t)(n0 + mt * 16 + lr) * H3 +
                                      ks * 32 + lg * 8);
        #pragma unroll
        for (int ntl = 0; ntl < 2; ++ntl) {
            const bf16x8 bf = *(const bf16x8*)(W4p +
                ((size_t)((w * 2 + ntl) * 32 + ks) * 64 + lane) * 8);
            #pragma unroll
            for (int mt = 0; mt < 2; ++mt)
                acc[mt][ntl] = mfma16(af[mt], bf, acc[mt][ntl]);
        }
    }
    #pragma unroll
    for (int ntl = 0; ntl < 2; ++ntl) {
        const int col = (w * 2 + ntl) * 16 + lr;
        const float sc = gamma[col] * rsqrtf(var[col] + 1e-5f);
        const float bo = beta[col] - mean[col] * sc;
        #pragma unroll
        for (int mt = 0; mt < 2; ++mt)
            #pragma unroll
            for (int r = 0; r < 4; ++r) {
                const int row = n0 + mt * 16 + lg * 4 + r;
                const float v = acc[mt][ntl][r] * sc + bo;
                out[(size_t)row * D + col] =
                    0.5f * (v + x0[(size_t)row * D + col]);
            }
    }
}

extern "C" void kernel_launch(void* const* d_in, const int* in_sizes, int n_in,
                              void* d_out, int out_size, void* d_ws, size_t ws_size,
                              hipStream_t stream)
{
    const float* x0    = (const float*)d_in[0];
    const int*   ei    = (const int*)d_in[1];
    const float* ea    = (const float*)d_in[2];
    const float* W1    = (const float*)d_in[3];
    const float* b1    = (const float*)d_in[4];
    const float* W2    = (const float*)d_in[5];
    const float* b2    = (const float*)d_in[6];
    const float* W3    = (const float*)d_in[7];
    const float* b3    = (const float*)d_in[8];
    const float* W4    = (const float*)d_in[9];
    const float* b4    = (const float*)d_in[10];
    const float* gamma = (const float*)d_in[11];
    const float* beta  = (const float*)d_in[12];
    const float* mean  = (const float*)d_in[13];
    const float* var   = (const float*)d_in[14];
    float* out = (float*)d_out;

    const int N = in_sizes[0] / D;   // 20000
    const int E = in_sizes[2] / D;   // 320000
    const int* src = ei;
    const int* dst = ei + E;

    char* ws = (char*)d_ws;
    float*  aggr = (float*)ws;
    ushort* t    = (ushort*)(ws + (size_t)N * H2 * 4);
    ushort* h    = t;   // alias: node_mlp1 writes h AFTER edge_gemm consumed t
    char*   p2   = (char*)(t + (size_t)E * D);
    int* cursor = (int*)p2;
    int* se     = cursor + N;
    int* de     = se + E;
    int* pe     = de + E;
    ushort* W1p = (ushort*)(pe + E);
    ushort* W2p = W1p + (size_t)(D  / 32) * (H1 / 16) * 512;
    ushort* W3p = W2p + (size_t)(H1 / 32) * (H2 / 16) * 512;
    ushort* W4p = W3p + (size_t)(K3 / 32) * (H3 / 16) * 512;

    hipMemsetAsync(aggr, 0, (size_t)N * H2 * sizeof(float), stream);
    hipMemsetAsync(cursor, 0, (size_t)N * sizeof(int), stream);

    pack_weights<<<(4096  + 255) / 256, 256, 0, stream>>>(W1, W1p, D,  H1);
    pack_weights<<<(16384 + 255) / 256, 256, 0, stream>>>(W2, W2p, H1, H2);
    pack_weights<<<(81920 + 255) / 256, 256, 0, stream>>>(W3, W3p, K3, H3);
    pack_weights<<<(16384 + 255) / 256, 256, 0, stream>>>(W4, W4p, H3, D);

    hist_kernel<<<(E + 255) / 256, 256, 0, stream>>>(dst, cursor, E);
    scan_kernel<<<1, 1024, 0, stream>>>(cursor, N);
    scatter_kernel<<<(E + 255) / 256, 256, 0, stream>>>(src, dst, cursor,
                                                        se, de, pe, E);

    gather_t<<<E / 16, 256, 0, stream>>>(x0, ea, se, pe, t);
    edge_gemm_mfma<<<E / TE, 512, 0, stream>>>(t, de, W1p, b1, W2p, b2, aggr);

    dim3 g1(N / TN, 2);
    node_mlp1_mfma<<<g1, 512, 0, stream>>>(x0, aggr, W3p, b3, h);
    node_mlp2_mfma<<<N / TN, 256, 0, stream>>>(h, x0, W4p, b4, gamma, beta, mean, var, out);
}